// Round 8
// baseline (91.644 us; speedup 1.0000x reference)
//
#include <hip/hip_runtime.h>
#include <math.h>

#define NN 8192
#define DD 512
#define MM 4
#define EE 131072
#define ITERS 2

typedef float  floatx2 __attribute__((ext_vector_type(2)));
typedef _Float16 h2    __attribute__((ext_vector_type(2)));
typedef _Float16 f16x8 __attribute__((ext_vector_type(8)));
typedef float  f32x4   __attribute__((ext_vector_type(4)));

union F8U { f16x8 v; h2 h[4]; uint2 u2[2]; };

__device__ inline h2 pkrtz(float a, float b) {
    return __builtin_bit_cast(h2, __builtin_amdgcn_cvt_pkrtz(a, b));
}

__device__ inline float fdot2a(h2 a, h2 b, float c) {
#if __has_builtin(__builtin_amdgcn_fdot2)
    return __builtin_amdgcn_fdot2(a, b, c, false);
#else
    return c + (float)a[0] * (float)b[0] + (float)a[1] * (float)b[1];
#endif
}

// Dequant 8 fp8 (uint2) -> f16x8. Exact (e4m3 subset of f16).
__device__ inline f16x8 deq8v(uint2 u) {
    F8U o;
    floatx2 f;
    f = __builtin_amdgcn_cvt_pk_f32_fp8((int)u.x, false); o.h[0] = pkrtz(f[0], f[1]);
    f = __builtin_amdgcn_cvt_pk_f32_fp8((int)u.x, true);  o.h[1] = pkrtz(f[0], f[1]);
    f = __builtin_amdgcn_cvt_pk_f32_fp8((int)u.y, false); o.h[2] = pkrtz(f[0], f[1]);
    f = __builtin_amdgcn_cvt_pk_f32_fp8((int)u.y, true);  o.h[3] = pkrtz(f[0], f[1]);
    return o.v;
}

template <int CTRL>
__device__ inline float dpp_add(float v) {
    int x = __builtin_amdgcn_update_dpp(0, __builtin_bit_cast(int, v), CTRL, 0xf, 0xf, true);
    return v + __builtin_bit_cast(float, x);
}

// ---------------------------------------------------------------------------
// Kernel 1: quantize emb rows to fp8 e4m3; reciprocal norms from the SAME
// dequantized f16 values and pkrtz'd squared weights the pair kernel uses.
// rn stored TRANSPOSED: rn_t[m][n]. One wave per node. Zeroes out[0].
// ---------------------------------------------------------------------------
__global__ __launch_bounds__(256) void quant_norm_kernel(const float* __restrict__ emb,
                                                         const float* __restrict__ mh,
                                                         uint2* __restrict__ q,
                                                         float* __restrict__ rn_t,
                                                         float* __restrict__ out) {
    if (blockIdx.x == 0 && threadIdx.x == 0) out[0] = 0.0f;

    const int lane = threadIdx.x & 63;
    const unsigned n = blockIdx.x * 4 + (threadIdx.x >> 6);

    const float* er = emb + n * DD + lane * 8;
    float4 e0 = *(const float4*)(er);
    float4 e1 = *(const float4*)(er + 4);

    int lo = 0, hi = 0;
    lo = __builtin_amdgcn_cvt_pk_fp8_f32(e0.x, e0.y, lo, false);
    lo = __builtin_amdgcn_cvt_pk_fp8_f32(e0.z, e0.w, lo, true);
    hi = __builtin_amdgcn_cvt_pk_fp8_f32(e1.x, e1.y, hi, false);
    hi = __builtin_amdgcn_cvt_pk_fp8_f32(e1.z, e1.w, hi, true);

    uint2 u = make_uint2((unsigned)lo, (unsigned)hi);
    q[(n << 6) | lane] = u;

    F8U A; A.v = deq8v(u);
    h2 p0 = A.h[0] * A.h[0];
    h2 p1 = A.h[1] * A.h[1];
    h2 p2 = A.h[2] * A.h[2];
    h2 p3 = A.h[3] * A.h[3];

    const float* mb = mh + lane * 8;
    float ss[4];
    #pragma unroll
    for (int m = 0; m < 4; ++m) {
        float4 m0 = *(const float4*)(mb + m * DD);
        float4 m1 = *(const float4*)(mb + m * DD + 4);
        h2 w0 = pkrtz(m0.x * m0.x, m0.y * m0.y);
        h2 w1 = pkrtz(m0.z * m0.z, m0.w * m0.w);
        h2 w2 = pkrtz(m1.x * m1.x, m1.y * m1.y);
        h2 w3 = pkrtz(m1.z * m1.z, m1.w * m1.w);
        float s = 0.f;
        s = fdot2a(p0, w0, s);
        s = fdot2a(p1, w1, s);
        s = fdot2a(p2, w2, s);
        s = fdot2a(p3, w3, s);
        ss[m] = s;
    }

    ss[0] = dpp_add<0x111>(ss[0]); ss[1] = dpp_add<0x111>(ss[1]);
    ss[2] = dpp_add<0x111>(ss[2]); ss[3] = dpp_add<0x111>(ss[3]);
    ss[0] = dpp_add<0x112>(ss[0]); ss[1] = dpp_add<0x112>(ss[1]);
    ss[2] = dpp_add<0x112>(ss[2]); ss[3] = dpp_add<0x112>(ss[3]);
    ss[0] = dpp_add<0x114>(ss[0]); ss[1] = dpp_add<0x114>(ss[1]);
    ss[2] = dpp_add<0x114>(ss[2]); ss[3] = dpp_add<0x114>(ss[3]);
    ss[0] = dpp_add<0x118>(ss[0]); ss[1] = dpp_add<0x118>(ss[1]);
    ss[2] = dpp_add<0x118>(ss[2]); ss[3] = dpp_add<0x118>(ss[3]);
    ss[0] = dpp_add<0x142>(ss[0]); ss[1] = dpp_add<0x142>(ss[1]);
    ss[2] = dpp_add<0x142>(ss[2]); ss[3] = dpp_add<0x142>(ss[3]);
    ss[0] = dpp_add<0x143>(ss[0]); ss[1] = dpp_add<0x143>(ss[1]);
    ss[2] = dpp_add<0x143>(ss[2]); ss[3] = dpp_add<0x143>(ss[3]);

    if (lane == 63) {
        rn_t[0 * NN + n] = 1.0f / fmaxf(sqrtf(ss[0]), 1e-12f);
        rn_t[1 * NN + n] = 1.0f / fmaxf(sqrtf(ss[1]), 1e-12f);
        rn_t[2 * NN + n] = 1.0f / fmaxf(sqrtf(ss[2]), 1e-12f);
        rn_t[3 * NN + n] = 1.0f / fmaxf(sqrtf(ss[3]), 1e-12f);
    }
}

// ---------------------------------------------------------------------------
// Kernel 2 (MFMA): 16 pairs per wave-iteration via mfma_f32_16x16x32_f16.
// A[row=pair (lane&15)][k=(lane>>4)*8+e] = f16 products a⊙b (dequant fp8).
// B[k][col] = w2[col&3][k]  (m replicated over the 16 cols), staged in LDS
// as 16B slots s = kk*16 + kq*4 + m so reads are ~conflict-free.
// D[row=pair=(lane>>4)*4+reg][col=lane&15 -> m=(col&3)]: m-sum = 2 DPP adds.
// ---------------------------------------------------------------------------
__global__ __launch_bounds__(256) void pair_kernel(const int* __restrict__ edges,
                                                   const int* __restrict__ nedges,
                                                   const unsigned char* __restrict__ qtab,
                                                   const float* __restrict__ mh,
                                                   const float* __restrict__ rn_t,
                                                   float* __restrict__ out) {
    __shared__ _Float16 wlds[2048];   // 4KB: 256 slots x 8 f16
    __shared__ float wsum[4];

    const int t = threadIdx.x;
    {   // stage squared f16 weights
        int m = t >> 6, sl = t & 63;
        const float* mb = mh + m * DD + sl * 8;
        float4 m0 = *(const float4*)(mb);
        float4 m1 = *(const float4*)(mb + 4);
        F8U wv;
        wv.h[0] = pkrtz(m0.x * m0.x, m0.y * m0.y);
        wv.h[1] = pkrtz(m0.z * m0.z, m0.w * m0.w);
        wv.h[2] = pkrtz(m1.x * m1.x, m1.y * m1.y);
        wv.h[3] = pkrtz(m1.z * m1.z, m1.w * m1.w);
        int s = (sl >> 2) * 16 + (sl & 3) * 4 + m;   // kk*16 + kq*4 + m
        *(f16x8*)(&wlds[s * 8]) = wv.v;
    }
    __syncthreads();

    const int lane   = t & 63;
    const int waveId = t >> 6;
    const int p      = lane & 15;     // pair-row / B-col
    const int kq     = lane >> 4;     // k-quad
    const int gw     = blockIdx.x * 4 + waveId;   // 8192 waves

    const _Float16* wbase = &wlds[(kq * 4 + (p & 3)) * 8];

    float lsum = 0.f;

    #pragma unroll 1
    for (int it = 0; it < ITERS; ++it) {
        const int  base = (gw * ITERS + it) * 16;
        const bool pos  = base < EE;
        const int* eb   = pos ? edges : nedges;
        const int  lb   = pos ? base : base - EE;

        const int i = eb[lb + p];
        const int j = eb[lb + EE + p];
        const unsigned char* qi = qtab + ((size_t)(unsigned)i << 9) + kq * 8;
        const unsigned char* qj = qtab + ((size_t)(unsigned)j << 9) + kq * 8;

        // epilogue operands issued early (overlap with MFMA loop)
        int4 pi4 = *(const int4*)(eb + lb + kq * 4);
        int4 pj4 = *(const int4*)(eb + lb + EE + kq * 4);
        const float* rm = rn_t + (p & 3) * NN;
        float w0 = rm[pi4.x] * rm[pj4.x];
        float w1 = rm[pi4.y] * rm[pj4.y];
        float w2 = rm[pi4.z] * rm[pj4.z];
        float w3 = rm[pi4.w] * rm[pj4.w];

        f32x4 acc = {0.f, 0.f, 0.f, 0.f};
        #pragma unroll
        for (int kk = 0; kk < 16; ++kk) {
            uint2 ua = *(const uint2*)(qi + kk * 32);
            uint2 ub = *(const uint2*)(qj + kk * 32);
            F8U pa, pb, pr;
            pa.v = deq8v(ua);
            pb.v = deq8v(ub);
            pr.h[0] = pa.h[0] * pb.h[0];
            pr.h[1] = pa.h[1] * pb.h[1];
            pr.h[2] = pa.h[2] * pb.h[2];
            pr.h[3] = pa.h[3] * pb.h[3];
            f16x8 bw = *(const f16x8*)(wbase + kk * 128);
            acc = __builtin_amdgcn_mfma_f32_16x16x32_f16(pr.v, bw, acc, 0, 0, 0);
        }

        // v_r = Sum_m acc_m[r] * rn[i_r][m] * rn[j_r][m]; m lives in lane&3
        float v0 = acc[0] * w0;
        float v1 = acc[1] * w1;
        float v2 = acc[2] * w2;
        float v3 = acc[3] * w3;
        v0 = dpp_add<0x111>(v0); v1 = dpp_add<0x111>(v1);
        v2 = dpp_add<0x111>(v2); v3 = dpp_add<0x111>(v3);
        v0 = dpp_add<0x112>(v0); v1 = dpp_add<0x112>(v1);
        v2 = dpp_add<0x112>(v2); v3 = dpp_add<0x112>(v3);
        // lane p==3 (per kq row) now holds the full m-sums for pairs kq*4+0..3

        float d0 = 1.000001f - 0.25f * v0;
        float d1 = 1.000001f - 0.25f * v1;
        float d2 = 1.000001f - 0.25f * v2;
        float d3 = 1.000001f - 0.25f * v3;
        float a0 = pos ? d0 : fmaf(-0.5f, d0, 1.0f);
        float a1 = pos ? d1 : fmaf(-0.5f, d1, 1.0f);
        float a2 = pos ? d2 : fmaf(-0.5f, d2, 1.0f);
        float a3 = pos ? d3 : fmaf(-0.5f, d3, 1.0f);
        float lg = __logf(fmaxf(a0, 1e-8f)) + __logf(fmaxf(a1, 1e-8f)) +
                   __logf(fmaxf(a2, 1e-8f)) + __logf(fmaxf(a3, 1e-8f));
        lsum += (p == 3) ? lg : 0.f;
    }

    // final 64-lane reduce (nonzero only in lanes 3,19,35,51)
    lsum = dpp_add<0x111>(lsum);
    lsum = dpp_add<0x112>(lsum);
    lsum = dpp_add<0x114>(lsum);
    lsum = dpp_add<0x118>(lsum);
    lsum = dpp_add<0x142>(lsum);
    lsum = dpp_add<0x143>(lsum);

    if (lane == 63) wsum[waveId] = lsum;
    __syncthreads();
    if (t == 0) {
        float s = wsum[0] + wsum[1] + wsum[2] + wsum[3];
        atomicAdd(out, -s);
    }
}

extern "C" void kernel_launch(void* const* d_in, const int* in_sizes, int n_in,
                              void* d_out, int out_size, void* d_ws, size_t ws_size,
                              hipStream_t stream) {
    const int*   edges  = (const int*)d_in[0];
    const int*   nedges = (const int*)d_in[1];
    const float* emb    = (const float*)d_in[2];
    const float* mh     = (const float*)d_in[3];
    float* out = (float*)d_out;

    uint2* q    = (uint2*)d_ws;                                  // 4 MiB fp8 table
    float* rn_t = (float*)((char*)d_ws + (size_t)NN * DD);       // 128 KiB, [m][n]

    quant_norm_kernel<<<NN / 4, 256, 0, stream>>>(emb, mh, q, rn_t, out);
    pair_kernel<<<2048, 256, 0, stream>>>(edges, nedges, (const unsigned char*)q,
                                          mh, rn_t, out);
}

// Round 9
// 87.472 us; speedup vs baseline: 1.0477x; 1.0477x over previous
//
#include <hip/hip_runtime.h>
#include <math.h>

#define NN 8192
#define DD 512
#define MM 4
#define EE 131072
#define SLOT 1056
#define REGION (16 * SLOT)   // 16896 B per buffer
#define NB 4                 // batches of 16 pairs per block

typedef float  floatx2 __attribute__((ext_vector_type(2)));
typedef _Float16 h2    __attribute__((ext_vector_type(2)));
typedef _Float16 f16x8 __attribute__((ext_vector_type(8)));
typedef float  f32x4   __attribute__((ext_vector_type(4)));

union F8U { f16x8 v; h2 h[4]; uint2 u2[2]; };

__device__ inline h2 pkrtz(float a, float b) {
    return __builtin_bit_cast(h2, __builtin_amdgcn_cvt_pkrtz(a, b));
}

__device__ inline float fdot2a(h2 a, h2 b, float c) {
#if __has_builtin(__builtin_amdgcn_fdot2)
    return __builtin_amdgcn_fdot2(a, b, c, false);
#else
    return c + (float)a[0] * (float)b[0] + (float)a[1] * (float)b[1];
#endif
}

// Dequant 8 fp8 (uint2) -> f16x8. Exact (e4m3 subset of f16).
__device__ inline f16x8 deq8v(uint2 u) {
    F8U o;
    floatx2 f;
    f = __builtin_amdgcn_cvt_pk_f32_fp8((int)u.x, false); o.h[0] = pkrtz(f[0], f[1]);
    f = __builtin_amdgcn_cvt_pk_f32_fp8((int)u.x, true);  o.h[1] = pkrtz(f[0], f[1]);
    f = __builtin_amdgcn_cvt_pk_f32_fp8((int)u.y, false); o.h[2] = pkrtz(f[0], f[1]);
    f = __builtin_amdgcn_cvt_pk_f32_fp8((int)u.y, true);  o.h[3] = pkrtz(f[0], f[1]);
    return o.v;
}

template <int CTRL>
__device__ inline float dpp_add(float v) {
    int x = __builtin_amdgcn_update_dpp(0, __builtin_bit_cast(int, v), CTRL, 0xf, 0xf, true);
    return v + __builtin_bit_cast(float, x);
}

// Async global->LDS: per-lane global src, uniform LDS base (+lane*16 in HW).
__device__ inline void dma16(const void* g, void* l) {
    __builtin_amdgcn_global_load_lds(
        (const __attribute__((address_space(1))) void*)g,
        (__attribute__((address_space(3))) void*)l, 16, 0, 0);
}

// ---------------------------------------------------------------------------
// Kernel 1: quantize emb rows to fp8 e4m3; reciprocal norms from the SAME
// dequantized f16 values and pkrtz'd squared weights the pair kernel uses.
// rn stored TRANSPOSED: rn_t[m][n]. One wave per node. Zeroes out[0].
// (verified in round 8 — unchanged)
// ---------------------------------------------------------------------------
__global__ __launch_bounds__(256) void quant_norm_kernel(const float* __restrict__ emb,
                                                         const float* __restrict__ mh,
                                                         uint2* __restrict__ q,
                                                         float* __restrict__ rn_t,
                                                         float* __restrict__ out) {
    if (blockIdx.x == 0 && threadIdx.x == 0) out[0] = 0.0f;

    const int lane = threadIdx.x & 63;
    const unsigned n = blockIdx.x * 4 + (threadIdx.x >> 6);

    const float* er = emb + n * DD + lane * 8;
    float4 e0 = *(const float4*)(er);
    float4 e1 = *(const float4*)(er + 4);

    int lo = 0, hi = 0;
    lo = __builtin_amdgcn_cvt_pk_fp8_f32(e0.x, e0.y, lo, false);
    lo = __builtin_amdgcn_cvt_pk_fp8_f32(e0.z, e0.w, lo, true);
    hi = __builtin_amdgcn_cvt_pk_fp8_f32(e1.x, e1.y, hi, false);
    hi = __builtin_amdgcn_cvt_pk_fp8_f32(e1.z, e1.w, hi, true);

    uint2 u = make_uint2((unsigned)lo, (unsigned)hi);
    q[(n << 6) | lane] = u;

    F8U A; A.v = deq8v(u);
    h2 p0 = A.h[0] * A.h[0];
    h2 p1 = A.h[1] * A.h[1];
    h2 p2 = A.h[2] * A.h[2];
    h2 p3 = A.h[3] * A.h[3];

    const float* mb = mh + lane * 8;
    float ss[4];
    #pragma unroll
    for (int m = 0; m < 4; ++m) {
        float4 m0 = *(const float4*)(mb + m * DD);
        float4 m1 = *(const float4*)(mb + m * DD + 4);
        h2 w0 = pkrtz(m0.x * m0.x, m0.y * m0.y);
        h2 w1 = pkrtz(m0.z * m0.z, m0.w * m0.w);
        h2 w2 = pkrtz(m1.x * m1.x, m1.y * m1.y);
        h2 w3 = pkrtz(m1.z * m1.z, m1.w * m1.w);
        float s = 0.f;
        s = fdot2a(p0, w0, s);
        s = fdot2a(p1, w1, s);
        s = fdot2a(p2, w2, s);
        s = fdot2a(p3, w3, s);
        ss[m] = s;
    }

    ss[0] = dpp_add<0x111>(ss[0]); ss[1] = dpp_add<0x111>(ss[1]);
    ss[2] = dpp_add<0x111>(ss[2]); ss[3] = dpp_add<0x111>(ss[3]);
    ss[0] = dpp_add<0x112>(ss[0]); ss[1] = dpp_add<0x112>(ss[1]);
    ss[2] = dpp_add<0x112>(ss[2]); ss[3] = dpp_add<0x112>(ss[3]);
    ss[0] = dpp_add<0x114>(ss[0]); ss[1] = dpp_add<0x114>(ss[1]);
    ss[2] = dpp_add<0x114>(ss[2]); ss[3] = dpp_add<0x114>(ss[3]);
    ss[0] = dpp_add<0x118>(ss[0]); ss[1] = dpp_add<0x118>(ss[1]);
    ss[2] = dpp_add<0x118>(ss[2]); ss[3] = dpp_add<0x118>(ss[3]);
    ss[0] = dpp_add<0x142>(ss[0]); ss[1] = dpp_add<0x142>(ss[1]);
    ss[2] = dpp_add<0x142>(ss[2]); ss[3] = dpp_add<0x142>(ss[3]);
    ss[0] = dpp_add<0x143>(ss[0]); ss[1] = dpp_add<0x143>(ss[1]);
    ss[2] = dpp_add<0x143>(ss[2]); ss[3] = dpp_add<0x143>(ss[3]);

    if (lane == 63) {
        rn_t[0 * NN + n] = 1.0f / fmaxf(sqrtf(ss[0]), 1e-12f);
        rn_t[1 * NN + n] = 1.0f / fmaxf(sqrtf(ss[1]), 1e-12f);
        rn_t[2 * NN + n] = 1.0f / fmaxf(sqrtf(ss[2]), 1e-12f);
        rn_t[3 * NN + n] = 1.0f / fmaxf(sqrtf(ss[3]), 1e-12f);
    }
}

// ---------------------------------------------------------------------------
// Kernel 2 (MFMA + async LDS staging): one wave per block; NB batches of 16
// pairs. One global_load_lds per pair (lanes 0-31 = row i, 32-63 = row j ->
// 1KB contiguous slot). Double-buffered; vmcnt(16) fences batch t while
// batch t+1's 16 DMAs stay in flight. B-operand (squared f16 weights) lives
// in 64 VGPRs. Fragment/epilogue mapping identical to round 8 (verified).
// ---------------------------------------------------------------------------
__global__ __launch_bounds__(64) void pair_kernel(const int* __restrict__ edges,
                                                  const int* __restrict__ nedges,
                                                  const unsigned char* __restrict__ qtab,
                                                  const float* __restrict__ mh,
                                                  const float* __restrict__ rn_t,
                                                  float* __restrict__ out) {
    __shared__ unsigned char stage[2 * REGION];   // 33792 B

    const int lane = threadIdx.x;
    const int p  = lane & 15;     // pair-row / B-col
    const int kq = lane >> 4;     // k-quad
    const int m  = p & 3;

    // B-fragment weights in registers: bw[kk][e] = f16(mh[m][kk*32+kq*8+e]^2)
    const float* wsrc = mh + m * DD + kq * 8;
    f16x8 bw[16];
    #pragma unroll
    for (int kk = 0; kk < 16; ++kk) {
        float4 a = *(const float4*)(wsrc + kk * 32);
        float4 b = *(const float4*)(wsrc + kk * 32 + 4);
        F8U t;
        t.h[0] = pkrtz(a.x * a.x, a.y * a.y);
        t.h[1] = pkrtz(a.z * a.z, a.w * a.w);
        t.h[2] = pkrtz(b.x * b.x, b.y * b.y);
        t.h[3] = pkrtz(b.z * b.z, b.w * b.w);
        bw[kk] = t.v;
    }

    const int  base = blockIdx.x * (NB * 16);
    const bool pos  = base < EE;
    const int* eb   = pos ? edges : nedges;
    const int  lb   = pos ? base : base - EE;

    const float* rm = rn_t + m * NN;

    // ---- prologue: batch 0 epilogue operands + batch 0 DMA ----
    int4 pi = *(const int4*)(eb + lb + kq * 4);
    int4 pj = *(const int4*)(eb + EE + lb + kq * 4);
    float ra0 = rm[pi.x], rb0 = rm[pj.x];
    float ra1 = rm[pi.y], rb1 = rm[pj.y];
    float ra2 = rm[pi.z], rb2 = rm[pj.z];
    float ra3 = rm[pi.w], rb3 = rm[pj.w];

    #pragma unroll
    for (int s = 0; s < 16; ++s) {
        int is = eb[lb + s];
        int js = eb[lb + EE + s];
        int row = (lane < 32) ? is : js;
        const unsigned char* src = qtab + ((size_t)(unsigned)row << 9) + (lane & 31) * 16;
        dma16(src, stage + s * SLOT);
    }

    float lsum = 0.f;

    for (int bt = 0; bt < NB; ++bt) {
        const unsigned char* buf = stage + (bt & 1) * REGION;

        float nra0 = 0.f, nrb0 = 0.f, nra1 = 0.f, nrb1 = 0.f;
        float nra2 = 0.f, nrb2 = 0.f, nra3 = 0.f, nrb3 = 0.f;
        if (bt < NB - 1) {
            const int nlb = lb + (bt + 1) * 16;
            int4 npi = *(const int4*)(eb + nlb + kq * 4);
            int4 npj = *(const int4*)(eb + EE + nlb + kq * 4);
            nra0 = rm[npi.x]; nrb0 = rm[npj.x];
            nra1 = rm[npi.y]; nrb1 = rm[npj.y];
            nra2 = rm[npi.z]; nrb2 = rm[npj.z];
            nra3 = rm[npi.w]; nrb3 = rm[npj.w];
            unsigned char* nbuf = stage + ((bt + 1) & 1) * REGION;
            #pragma unroll
            for (int s = 0; s < 16; ++s) {
                int is = eb[nlb + s];
                int js = eb[nlb + EE + s];
                int row = (lane < 32) ? is : js;
                const unsigned char* src = qtab + ((size_t)(unsigned)row << 9) + (lane & 31) * 16;
                dma16(src, nbuf + s * SLOT);
            }
            asm volatile("s_waitcnt vmcnt(16)" ::: "memory");
        } else {
            asm volatile("s_waitcnt vmcnt(0)" ::: "memory");
        }
        __builtin_amdgcn_sched_barrier(0);

        const unsigned char* rbase = buf + p * SLOT + kq * 8;
        f32x4 acc = {0.f, 0.f, 0.f, 0.f};
        #pragma unroll
        for (int kk = 0; kk < 16; ++kk) {
            uint2 ua = *(const uint2*)(rbase + kk * 32);
            uint2 ub = *(const uint2*)(rbase + 512 + kk * 32);
            F8U pa, pb, pr;
            pa.v = deq8v(ua);
            pb.v = deq8v(ub);
            pr.h[0] = pa.h[0] * pb.h[0];
            pr.h[1] = pa.h[1] * pb.h[1];
            pr.h[2] = pa.h[2] * pb.h[2];
            pr.h[3] = pa.h[3] * pb.h[3];
            acc = __builtin_amdgcn_mfma_f32_16x16x32_f16(pr.v, bw[kk], acc, 0, 0, 0);
        }

        // v_r = Sum_m acc_m[r] * rn[i_r][m] * rn[j_r][m]; m lives in lane&3
        float v0 = acc[0] * (ra0 * rb0);
        float v1 = acc[1] * (ra1 * rb1);
        float v2 = acc[2] * (ra2 * rb2);
        float v3 = acc[3] * (ra3 * rb3);
        v0 = dpp_add<0x111>(v0); v1 = dpp_add<0x111>(v1);
        v2 = dpp_add<0x111>(v2); v3 = dpp_add<0x111>(v3);
        v0 = dpp_add<0x112>(v0); v1 = dpp_add<0x112>(v1);
        v2 = dpp_add<0x112>(v2); v3 = dpp_add<0x112>(v3);
        // lane p==3 (per kq row) holds full m-sums for pairs kq*4 + 0..3

        float d0 = 1.000001f - 0.25f * v0;
        float d1 = 1.000001f - 0.25f * v1;
        float d2 = 1.000001f - 0.25f * v2;
        float d3 = 1.000001f - 0.25f * v3;
        float a0 = pos ? d0 : fmaf(-0.5f, d0, 1.0f);
        float a1 = pos ? d1 : fmaf(-0.5f, d1, 1.0f);
        float a2 = pos ? d2 : fmaf(-0.5f, d2, 1.0f);
        float a3 = pos ? d3 : fmaf(-0.5f, d3, 1.0f);
        float lg = __logf(fmaxf(a0, 1e-8f)) + __logf(fmaxf(a1, 1e-8f)) +
                   __logf(fmaxf(a2, 1e-8f)) + __logf(fmaxf(a3, 1e-8f));
        lsum += (p == 3) ? lg : 0.f;

        ra0 = nra0; rb0 = nrb0; ra1 = nra1; rb1 = nrb1;
        ra2 = nra2; rb2 = nrb2; ra3 = nra3; rb3 = nrb3;
    }

    // final 64-lane reduce (nonzero only in lanes 3,19,35,51)
    lsum = dpp_add<0x111>(lsum);
    lsum = dpp_add<0x112>(lsum);
    lsum = dpp_add<0x114>(lsum);
    lsum = dpp_add<0x118>(lsum);
    lsum = dpp_add<0x142>(lsum);
    lsum = dpp_add<0x143>(lsum);

    if (lane == 63) atomicAdd(out, -lsum);
}

extern "C" void kernel_launch(void* const* d_in, const int* in_sizes, int n_in,
                              void* d_out, int out_size, void* d_ws, size_t ws_size,
                              hipStream_t stream) {
    const int*   edges  = (const int*)d_in[0];
    const int*   nedges = (const int*)d_in[1];
    const float* emb    = (const float*)d_in[2];
    const float* mh     = (const float*)d_in[3];
    float* out = (float*)d_out;

    uint2* q    = (uint2*)d_ws;                                  // 4 MiB fp8 table
    float* rn_t = (float*)((char*)d_ws + (size_t)NN * DD);       // 128 KiB, [m][n]

    quant_norm_kernel<<<NN / 4, 256, 0, stream>>>(emb, mh, q, rn_t, out);
    pair_kernel<<<(2 * EE) / (NB * 16), 64, 0, stream>>>(edges, nedges,
                                                         (const unsigned char*)q,
                                                         mh, rn_t, out);
}